// Round 1
// baseline (610.536 us; speedup 1.0000x reference)
//
#include <hip/hip_runtime.h>

#define NB 32
#define NL 512
#define ND 512
#define NH 1024
#define NE 8
#define BM 16        // rows per block
#define KT 32        // k-tile
#define NROWS (NB * NL)

// Fused: decomp + dual GEMM + LN + relu-add + W2 logits + softmax + top2
// One block = 16 consecutive (b,l) rows (same b since 16 | 512), full H=1024.
__global__ __launch_bounds__(256) void fused_main(
    const float* __restrict__ x,
    const float* __restrict__ Wt, const float* __restrict__ bt,
    const float* __restrict__ gt, const float* __restrict__ bet,
    const float* __restrict__ Ws, const float* __restrict__ bs,
    const float* __restrict__ gs, const float* __restrict__ bes,
    const float* __restrict__ W2, const float* __restrict__ b2,
    unsigned* __restrict__ mb, float* __restrict__ gates)
{
    __shared__ float xt[BM + 24][KT];   // x tile with +-12 halo (clamped)
    __shared__ float At[BM][KT];        // trend tile
    __shared__ float As[BM][KT];        // seasonal tile
    __shared__ float red[BM][4][4];     // per-row LN partials (4 waves x {st,qt,ss,qs})
    __shared__ float lgp[BM][4][NE];    // per-row logit partials per wave

    const int tid  = threadIdx.x;
    const int lane = tid & 63;
    const int wave = tid >> 6;
    const int row0 = blockIdx.x * BM;
    const int b    = row0 / NL;
    const int l0   = row0 % NL;

    float acc_t[BM][4], acc_s[BM][4];
    #pragma unroll
    for (int r = 0; r < BM; ++r)
        #pragma unroll
        for (int i = 0; i < 4; ++i) { acc_t[r][i] = 0.f; acc_s[r][i] = 0.f; }

    const float* xb = x + (size_t)b * NL * ND;

    for (int k0 = 0; k0 < ND; k0 += KT) {
        __syncthreads();
        // stage x rows [l0-12, l0+27], clamped to [0, NL-1] (replicate pad)
        #pragma unroll
        for (int j = 0; j < 5; ++j) {
            int idx = tid + 256 * j;          // (BM+24)*KT = 1280 = 5*256
            int rr = idx >> 5;                // KT == 32
            int cc = idx & 31;
            int ll = l0 - 12 + rr;
            ll = ll < 0 ? 0 : (ll > NL - 1 ? NL - 1 : ll);
            xt[rr][cc] = xb[(size_t)ll * ND + k0 + cc];
        }
        __syncthreads();
        // moving average (25-tap) -> trend / seasonal tiles
        #pragma unroll
        for (int j = 0; j < 2; ++j) {
            int e  = tid + 256 * j;           // BM*KT = 512 = 2*256
            int rr = e >> 5, cc = e & 31;
            float s = 0.f;
            #pragma unroll
            for (int t = 0; t < 25; ++t) s += xt[rr + t][cc];
            float ma = s * (1.0f / 25.0f);
            At[rr][cc] = xt[rr + 12][cc] - ma;
            As[rr][cc] = ma;
        }
        __syncthreads();
        // dual register GEMM: acc_{t,s}[r][i] over 4 columns c = tid + 256*i
        for (int kk = 0; kk < KT; kk += 4) {
            float wtv[4][4], wsv[4][4];
            #pragma unroll
            for (int q = 0; q < 4; ++q) {
                const float* wtp = Wt + (size_t)(k0 + kk + q) * NH;
                const float* wsp = Ws + (size_t)(k0 + kk + q) * NH;
                #pragma unroll
                for (int i = 0; i < 4; ++i) {
                    wtv[q][i] = wtp[tid + 256 * i];
                    wsv[q][i] = wsp[tid + 256 * i];
                }
            }
            #pragma unroll
            for (int r = 0; r < BM; ++r) {
                float4 at  = *(const float4*)&At[r][kk];
                float4 as2 = *(const float4*)&As[r][kk];
                #pragma unroll
                for (int i = 0; i < 4; ++i) {
                    acc_t[r][i] = fmaf(at.x,  wtv[0][i], acc_t[r][i]);
                    acc_t[r][i] = fmaf(at.y,  wtv[1][i], acc_t[r][i]);
                    acc_t[r][i] = fmaf(at.z,  wtv[2][i], acc_t[r][i]);
                    acc_t[r][i] = fmaf(at.w,  wtv[3][i], acc_t[r][i]);
                    acc_s[r][i] = fmaf(as2.x, wsv[0][i], acc_s[r][i]);
                    acc_s[r][i] = fmaf(as2.y, wsv[1][i], acc_s[r][i]);
                    acc_s[r][i] = fmaf(as2.z, wsv[2][i], acc_s[r][i]);
                    acc_s[r][i] = fmaf(as2.w, wsv[3][i], acc_s[r][i]);
                }
            }
        }
    }

    // --- epilogue ---
    float btv[4], bsv[4], gtv[4], betv[4], gsv[4], besv[4];
    #pragma unroll
    for (int i = 0; i < 4; ++i) {
        int c = tid + 256 * i;
        btv[i]  = bt[c];  bsv[i]  = bs[c];
        gtv[i]  = gt[c];  betv[i] = bet[c];
        gsv[i]  = gs[c];  besv[i] = bes[c];
    }
    #pragma unroll
    for (int r = 0; r < BM; ++r)
        #pragma unroll
        for (int i = 0; i < 4; ++i) { acc_t[r][i] += btv[i]; acc_s[r][i] += bsv[i]; }

    // per-row LN stats: sum and sumsq for t and s
    #pragma unroll
    for (int r = 0; r < BM; ++r) {
        float st = 0.f, qt = 0.f, ss = 0.f, qs = 0.f;
        #pragma unroll
        for (int i = 0; i < 4; ++i) {
            st += acc_t[r][i]; qt += acc_t[r][i] * acc_t[r][i];
            ss += acc_s[r][i]; qs += acc_s[r][i] * acc_s[r][i];
        }
        for (int o = 32; o; o >>= 1) {
            st += __shfl_xor(st, o); qt += __shfl_xor(qt, o);
            ss += __shfl_xor(ss, o); qs += __shfl_xor(qs, o);
        }
        if (lane == 0) {
            red[r][wave][0] = st; red[r][wave][1] = qt;
            red[r][wave][2] = ss; red[r][wave][3] = qs;
        }
    }
    __syncthreads();

    // per-row: LN -> med = relu(t+s) -> logits partial (W2 from global/L1)
    #pragma unroll
    for (int r = 0; r < BM; ++r) {
        float st = red[r][0][0] + red[r][1][0] + red[r][2][0] + red[r][3][0];
        float qt = red[r][0][1] + red[r][1][1] + red[r][2][1] + red[r][3][1];
        float ss = red[r][0][2] + red[r][1][2] + red[r][2][2] + red[r][3][2];
        float qs = red[r][0][3] + red[r][1][3] + red[r][2][3] + red[r][3][3];
        float mut = st * (1.f / NH);
        float rt  = rsqrtf(qt * (1.f / NH) - mut * mut + 1e-5f);
        float mus = ss * (1.f / NH);
        float rs2 = rsqrtf(qs * (1.f / NH) - mus * mus + 1e-5f);

        float lg[NE];
        #pragma unroll
        for (int e = 0; e < NE; ++e) lg[e] = 0.f;
        #pragma unroll
        for (int i = 0; i < 4; ++i) {
            int c = tid + 256 * i;
            float tv = (acc_t[r][i] - mut) * rt  * gtv[i] + betv[i];
            float sv = (acc_s[r][i] - mus) * rs2 * gsv[i] + besv[i];
            float m  = tv + sv;  m = m > 0.f ? m : 0.f;
            float4 w0 = *(const float4*)&W2[(size_t)c * NE];
            float4 w1 = *(const float4*)&W2[(size_t)c * NE + 4];
            lg[0] = fmaf(m, w0.x, lg[0]); lg[1] = fmaf(m, w0.y, lg[1]);
            lg[2] = fmaf(m, w0.z, lg[2]); lg[3] = fmaf(m, w0.w, lg[3]);
            lg[4] = fmaf(m, w1.x, lg[4]); lg[5] = fmaf(m, w1.y, lg[5]);
            lg[6] = fmaf(m, w1.z, lg[6]); lg[7] = fmaf(m, w1.w, lg[7]);
        }
        for (int o = 32; o; o >>= 1)
            #pragma unroll
            for (int e = 0; e < NE; ++e) lg[e] += __shfl_xor(lg[e], o);
        if (lane == 0)
            #pragma unroll
            for (int e = 0; e < NE; ++e) lgp[r][wave][e] = lg[e];
    }
    __syncthreads();

    // one thread per row: combine waves, softmax, top2, mask OR, gate store
    if (tid < BM) {
        int r = tid;
        float lg[NE];
        #pragma unroll
        for (int e = 0; e < NE; ++e)
            lg[e] = lgp[r][0][e] + lgp[r][1][e] + lgp[r][2][e] + lgp[r][3][e] + b2[e];
        float mx = lg[0];
        #pragma unroll
        for (int e = 1; e < NE; ++e) mx = lg[e] > mx ? lg[e] : mx;
        float p[NE]; float sum = 0.f;
        #pragma unroll
        for (int e = 0; e < NE; ++e) { p[e] = expf(lg[e] - mx); sum += p[e]; }
        float inv = 1.f / sum;
        #pragma unroll
        for (int e = 0; e < NE; ++e) p[e] *= inv;
        // top-2 (ties -> lower index first, matches jax.lax.top_k)
        int i0 = 0;
        #pragma unroll
        for (int e = 1; e < NE; ++e) if (lg[e] > lg[i0]) i0 = e;
        int i1 = i0 == 0 ? 1 : 0;
        #pragma unroll
        for (int e = 0; e < NE; ++e) if (e != i0 && lg[e] > lg[i1]) i1 = e;
        atomicOr(&mb[2 * b + 0], 1u << i0);
        atomicOr(&mb[2 * b + 1], 1u << i1);
        if (l0 == 0 && r < 8) {
            #pragma unroll
            for (int e = 0; e < NE; ++e)
                gates[((size_t)b * 8 + r) * NE + e] = p[e];
        }
    }
}

// masked = gates * maskbit; denom = sum_b + 1e-4; out = masked/denom*64
__global__ void finalize_k(const unsigned* __restrict__ mb,
                           const float* __restrict__ gates,
                           float* __restrict__ out)
{
    int t = threadIdx.x;
    if (t >= 16) return;
    int l = t >> 1, e = t & 1;
    float m[NB];
    float sum = 0.f;
    #pragma unroll
    for (int bb = 0; bb < NB; ++bb) {
        float g  = gates[((size_t)bb * 8 + l) * NE + e];
        float on = ((mb[2 * bb + e] >> l) & 1u) ? 1.f : 0.f;
        m[bb] = g * on;
        sum += m[bb];
    }
    float scale = 64.f / (sum + 1e-4f);   // capacity = int(2.0*32)
    #pragma unroll
    for (int bb = 0; bb < NB; ++bb)
        out[(size_t)bb * (NL * NE) + l * NE + e] = m[bb] * scale;
}

extern "C" void kernel_launch(void* const* d_in, const int* in_sizes, int n_in,
                              void* d_out, int out_size, void* d_ws, size_t ws_size,
                              hipStream_t stream) {
    const float* x   = (const float*)d_in[0];
    const float* Wt  = (const float*)d_in[1];
    const float* bt  = (const float*)d_in[2];
    const float* gt  = (const float*)d_in[3];
    const float* bet = (const float*)d_in[4];
    const float* Ws  = (const float*)d_in[5];
    const float* bs  = (const float*)d_in[6];
    const float* gs  = (const float*)d_in[7];
    const float* bes = (const float*)d_in[8];
    const float* W2  = (const float*)d_in[9];
    const float* b2  = (const float*)d_in[10];
    float* out = (float*)d_out;

    unsigned* mb = (unsigned*)d_ws;                    // 64 u32 mask bits
    float* gates = (float*)((char*)d_ws + 256);        // [32][8][8] floats

    hipMemsetAsync(d_out, 0, sizeof(float) * NB * NL * NE, stream);
    hipMemsetAsync(mb, 0, 256, stream);

    fused_main<<<NROWS / BM, 256, 0, stream>>>(
        x, Wt, bt, gt, bet, Ws, bs, gs, bes, W2, b2, mb, gates);
    finalize_k<<<1, 64, 0, stream>>>(mb, gates, out);
}

// Round 2
// 281.435 us; speedup vs baseline: 2.1694x; 2.1694x over previous
//
#include <hip/hip_runtime.h>

#define NB 32
#define NL 512
#define ND 512
#define NH 1024
#define NE 8
#define NROWS (NB * NL)
#define BM 64
#define THREADS 512

typedef __attribute__((ext_vector_type(8))) short bf16x8;
typedef __attribute__((ext_vector_type(4))) float f32x4;

__device__ __forceinline__ unsigned short f2bf(float f) {
    unsigned u = __float_as_uint(f);
    return (unsigned short)((u + 0x7fffu + ((u >> 16) & 1u)) >> 16);
}
__device__ __forceinline__ float bf2f(unsigned short b) {
    return __uint_as_float(((unsigned)b) << 16);
}

// ---------------- W prep: transpose + split to bf16 hi/lo, [N][K] ----------------
__global__ __launch_bounds__(256) void wprep(
    const float* __restrict__ Wt, const float* __restrict__ Ws,
    unsigned short* __restrict__ WtTh, unsigned short* __restrict__ WtTl,
    unsigned short* __restrict__ WsTh, unsigned short* __restrict__ WsTl)
{
    __shared__ float tile[64][65];
    int bid = blockIdx.x;
    int mat = bid >> 7, rem = bid & 127;
    int kt0 = (rem >> 4) << 6;   // 0..448
    int nt0 = (rem & 15) << 6;   // 0..960
    const float* W = mat ? Ws : Wt;
    unsigned short* Oh = mat ? WsTh : WtTh;
    unsigned short* Ol = mat ? WsTl : WtTl;
    int t = threadIdx.x;
    #pragma unroll
    for (int i = 0; i < 16; ++i) {
        int idx = t + 256 * i;
        int k = idx >> 6, n = idx & 63;
        tile[k][n] = W[(size_t)(kt0 + k) * NH + nt0 + n];
    }
    __syncthreads();
    #pragma unroll
    for (int i = 0; i < 16; ++i) {
        int idx = t + 256 * i;
        int n = idx >> 6, kk = idx & 63;
        float w = tile[kk][n];
        unsigned short hb = f2bf(w);
        unsigned short lb = f2bf(w - bf2f(hb));
        size_t o = (size_t)(nt0 + n) * ND + kt0 + kk;
        Oh[o] = hb;
        Ol[o] = lb;
    }
}

// ---------------- fused main: decomp + split-bf16 MFMA dual GEMM + LN + gate ----------------
union alignas(16) SmemA {
    struct {
        float xt[BM + 24][32];          // 11264 B
        unsigned Ah[4][BM][4];          // 4096 B  (packed 2x bf16, fragment order)
        unsigned Al[4][BM][4];          // 4096 B
    } ld;
    float lgp[BM][8][NE];               // 16384 B (logit partials, reused after k-loops)
};

__global__ __launch_bounds__(THREADS) void fused_mfma(
    const float* __restrict__ x,
    const float* __restrict__ bt, const float* __restrict__ gt, const float* __restrict__ bet,
    const float* __restrict__ bs, const float* __restrict__ gs, const float* __restrict__ bes,
    const float* __restrict__ W2, const float* __restrict__ b2,
    const unsigned short* __restrict__ WtTh, const unsigned short* __restrict__ WtTl,
    const unsigned short* __restrict__ WsTh, const unsigned short* __restrict__ WsTl,
    unsigned* __restrict__ mb, float* __restrict__ gates)
{
    __shared__ SmemA sA;
    __shared__ unsigned short tstash[BM][NH + 8];   // 132096 B, +8 pad kills 4-way conflict
    __shared__ float stats[BM][8][2];               // 4096 B
    __shared__ float rowstat[BM][2];                // 512 B

    const int tid  = threadIdx.x;
    const int lane = tid & 63;
    const int wave = tid >> 6;
    const int g    = lane >> 4;      // k-group (0..3) / C row-subgroup
    const int c    = lane & 15;      // fragment col (N) / A row (M)
    const int row0 = blockIdx.x * BM;
    const int b    = row0 >> 9;
    const int l0   = row0 & (NL - 1);
    const int n0w  = wave * 128;
    const float* xb = x + (size_t)b * NL * ND;

    for (int pass = 0; pass < 2; ++pass) {
        const unsigned short* Bh = pass ? WsTh : WtTh;
        const unsigned short* Bl = pass ? WsTl : WtTl;
        const float* bias = pass ? bs : bt;

        f32x4 acc[8][4];
        #pragma unroll
        for (int cf = 0; cf < 8; ++cf)
            #pragma unroll
            for (int mf = 0; mf < 4; ++mf)
                acc[cf][mf] = (f32x4){0.f, 0.f, 0.f, 0.f};

        for (int k0 = 0; k0 < ND; k0 += 32) {
            __syncthreads();
            // stage x rows [l0-12, l0+BM+11] clamped (replicate pad), k-slice of 32
            #pragma unroll
            for (int j = 0; j < 6; ++j) {
                int idx = tid + THREADS * j;
                if (idx < (BM + 24) * 32) {
                    int rr = idx >> 5, cc = idx & 31;
                    int ll = l0 - 12 + rr;
                    ll = ll < 0 ? 0 : (ll > NL - 1 ? NL - 1 : ll);
                    sA.ld.xt[rr][cc] = xb[(size_t)ll * ND + k0 + cc];
                }
            }
            __syncthreads();
            // moving avg -> trend(p0)/seasonal(p1) -> split bf16 in fragment order
            #pragma unroll
            for (int j = 0; j < 2; ++j) {
                int item = tid + THREADS * j;     // 64 rows x 16 kpairs
                int rr = item >> 4, kp = item & 15;
                int k = kp << 1;
                float s0 = 0.f, s1 = 0.f;
                #pragma unroll
                for (int t25 = 0; t25 < 25; ++t25) {
                    s0 += sA.ld.xt[rr + t25][k];
                    s1 += sA.ld.xt[rr + t25][k + 1];
                }
                float ma0 = s0 * (1.0f / 25.0f), ma1 = s1 * (1.0f / 25.0f);
                float a0, a1;
                if (pass == 0) { a0 = sA.ld.xt[rr + 12][k] - ma0; a1 = sA.ld.xt[rr + 12][k + 1] - ma1; }
                else           { a0 = ma0;                        a1 = ma1; }
                unsigned short h0 = f2bf(a0), h1 = f2bf(a1);
                unsigned short q0 = f2bf(a0 - bf2f(h0)), q1 = f2bf(a1 - bf2f(h1));
                sA.ld.Ah[kp >> 2][rr][kp & 3] = ((unsigned)h1 << 16) | h0;
                sA.ld.Al[kp >> 2][rr][kp & 3] = ((unsigned)q1 << 16) | q0;
            }
            __syncthreads();
            // A fragments: row = mf*16 + c, k = g*8 + j  (conflict-free b128)
            bf16x8 ah[4], al[4];
            #pragma unroll
            for (int mf = 0; mf < 4; ++mf) {
                ah[mf] = *(const bf16x8*)&sA.ld.Ah[g][mf * 16 + c][0];
                al[mf] = *(const bf16x8*)&sA.ld.Al[g][mf * 16 + c][0];
            }
            // B fragments from transposed split W (L2-resident), 3-term split MFMA
            #pragma unroll
            for (int cf = 0; cf < 8; ++cf) {
                size_t boff = (size_t)(n0w + cf * 16 + c) * ND + (k0 + g * 8);
                bf16x8 bh = *(const bf16x8*)&Bh[boff];
                bf16x8 bl = *(const bf16x8*)&Bl[boff];
                #pragma unroll
                for (int mf = 0; mf < 4; ++mf) {
                    acc[cf][mf] = __builtin_amdgcn_mfma_f32_16x16x32_bf16(ah[mf], bh, acc[cf][mf], 0, 0, 0);
                    acc[cf][mf] = __builtin_amdgcn_mfma_f32_16x16x32_bf16(al[mf], bh, acc[cf][mf], 0, 0, 0);
                    acc[cf][mf] = __builtin_amdgcn_mfma_f32_16x16x32_bf16(ah[mf], bl, acc[cf][mf], 0, 0, 0);
                }
            }
        }

        // ---- epilogue: bias, LN stats ----
        float bv[8];
        #pragma unroll
        for (int cf = 0; cf < 8; ++cf) bv[cf] = bias[n0w + cf * 16 + c];
        #pragma unroll
        for (int cf = 0; cf < 8; ++cf)
            #pragma unroll
            for (int mf = 0; mf < 4; ++mf)
                #pragma unroll
                for (int r = 0; r < 4; ++r) acc[cf][mf][r] += bv[cf];

        float svv[4][4], qvv[4][4];
        #pragma unroll
        for (int mf = 0; mf < 4; ++mf)
            #pragma unroll
            for (int r = 0; r < 4; ++r) {
                float s = 0.f, q = 0.f;
                #pragma unroll
                for (int cf = 0; cf < 8; ++cf) { float v = acc[cf][mf][r]; s += v; q += v * v; }
                #pragma unroll
                for (int o = 1; o < 16; o <<= 1) { s += __shfl_xor(s, o); q += __shfl_xor(q, o); }
                svv[mf][r] = s; qvv[mf][r] = q;
            }
        if (c == 0) {
            #pragma unroll
            for (int mf = 0; mf < 4; ++mf)
                #pragma unroll
                for (int r = 0; r < 4; ++r) {
                    int row = mf * 16 + g * 4 + r;
                    stats[row][wave][0] = svv[mf][r];
                    stats[row][wave][1] = qvv[mf][r];
                }
        }
        __syncthreads();
        if (tid < BM) {
            float s = 0.f, q = 0.f;
            #pragma unroll
            for (int w = 0; w < 8; ++w) { s += stats[tid][w][0]; q += stats[tid][w][1]; }
            float mu  = s * (1.0f / NH);
            float var = q * (1.0f / NH) - mu * mu;
            rowstat[tid][0] = mu;
            rowstat[tid][1] = rsqrtf(var + 1e-5f);
        }
        __syncthreads();

        if (pass == 0) {
            // stash LN(trend) as bf16
            float gv[8], bev[8];
            #pragma unroll
            for (int cf = 0; cf < 8; ++cf) { int nc = n0w + cf * 16 + c; gv[cf] = gt[nc]; bev[cf] = bet[nc]; }
            #pragma unroll
            for (int mf = 0; mf < 4; ++mf)
                #pragma unroll
                for (int r = 0; r < 4; ++r) {
                    int row = mf * 16 + g * 4 + r;
                    float mu = rowstat[row][0], rs = rowstat[row][1];
                    #pragma unroll
                    for (int cf = 0; cf < 8; ++cf) {
                        float v = (acc[cf][mf][r] - mu) * rs * gv[cf] + bev[cf];
                        tstash[row][n0w + cf * 16 + c] = f2bf(v);
                    }
                }
        } else {
            // LN(seasonal) + med=relu(t+s) + W2 logits
            float gv[8], bev[8];
            #pragma unroll
            for (int cf = 0; cf < 8; ++cf) { int nc = n0w + cf * 16 + c; gv[cf] = gs[nc]; bev[cf] = bes[nc]; }
            #pragma unroll
            for (int mf = 0; mf < 4; ++mf)
                #pragma unroll
                for (int r = 0; r < 4; ++r) {
                    int row = mf * 16 + g * 4 + r;
                    float mu = rowstat[row][0], rs = rowstat[row][1];
                    float lg[NE];
                    #pragma unroll
                    for (int e = 0; e < NE; ++e) lg[e] = 0.f;
                    #pragma unroll
                    for (int cf = 0; cf < 8; ++cf) {
                        int nc = n0w + cf * 16 + c;
                        float sv2 = (acc[cf][mf][r] - mu) * rs * gv[cf] + bev[cf];
                        float tv  = bf2f(tstash[row][nc]);
                        float m   = tv + sv2; m = m > 0.f ? m : 0.f;
                        const float4* w2p = (const float4*)&W2[(size_t)nc * NE];
                        float4 wa = w2p[0], wb = w2p[1];
                        lg[0] = fmaf(m, wa.x, lg[0]); lg[1] = fmaf(m, wa.y, lg[1]);
                        lg[2] = fmaf(m, wa.z, lg[2]); lg[3] = fmaf(m, wa.w, lg[3]);
                        lg[4] = fmaf(m, wb.x, lg[4]); lg[5] = fmaf(m, wb.y, lg[5]);
                        lg[6] = fmaf(m, wb.z, lg[6]); lg[7] = fmaf(m, wb.w, lg[7]);
                    }
                    #pragma unroll
                    for (int o = 1; o < 16; o <<= 1)
                        #pragma unroll
                        for (int e = 0; e < NE; ++e) lg[e] += __shfl_xor(lg[e], o);
                    if (c == 0)
                        #pragma unroll
                        for (int e = 0; e < NE; ++e) sA.lgp[row][wave][e] = lg[e];
                }
            __syncthreads();
            // per-row: combine waves, softmax, top2, mask bits, gate rows
            if (tid < BM) {
                int row = tid;
                float lg[NE];
                #pragma unroll
                for (int e = 0; e < NE; ++e) {
                    float s = b2[e];
                    #pragma unroll
                    for (int w = 0; w < 8; ++w) s += sA.lgp[row][w][e];
                    lg[e] = s;
                }
                float mx = lg[0];
                #pragma unroll
                for (int e = 1; e < NE; ++e) mx = lg[e] > mx ? lg[e] : mx;
                float p[NE]; float sum = 0.f;
                #pragma unroll
                for (int e = 0; e < NE; ++e) { p[e] = expf(lg[e] - mx); sum += p[e]; }
                float inv = 1.f / sum;
                int i0 = 0;
                #pragma unroll
                for (int e = 1; e < NE; ++e) if (lg[e] > lg[i0]) i0 = e;
                int i1 = i0 == 0 ? 1 : 0;
                #pragma unroll
                for (int e = 0; e < NE; ++e) if (e != i0 && lg[e] > lg[i1]) i1 = e;
                atomicOr(&mb[2 * b + 0], 1u << i0);
                atomicOr(&mb[2 * b + 1], 1u << i1);
                if (l0 == 0 && row < 8) {
                    #pragma unroll
                    for (int e = 0; e < NE; ++e)
                        gates[((size_t)b * 8 + row) * NE + e] = p[e] * inv;
                }
            }
        }
    }
}

// masked = gates * maskbit; denom = sum_b + 1e-4; out = masked/denom*64
__global__ void finalize_k(const unsigned* __restrict__ mb,
                           const float* __restrict__ gates,
                           float* __restrict__ out)
{
    int t = threadIdx.x;
    if (t >= 16) return;
    int l = t >> 1, e = t & 1;
    float m[NB];
    float sum = 0.f;
    #pragma unroll
    for (int bb = 0; bb < NB; ++bb) {
        float gvv = gates[((size_t)bb * 8 + l) * NE + e];
        float on  = ((mb[2 * bb + e] >> l) & 1u) ? 1.f : 0.f;
        m[bb] = gvv * on;
        sum += m[bb];
    }
    float scale = 64.f / (sum + 1e-4f);   // capacity = int(2.0*32)
    #pragma unroll
    for (int bb = 0; bb < NB; ++bb)
        out[(size_t)bb * (NL * NE) + l * NE + e] = m[bb] * scale;
}

extern "C" void kernel_launch(void* const* d_in, const int* in_sizes, int n_in,
                              void* d_out, int out_size, void* d_ws, size_t ws_size,
                              hipStream_t stream) {
    const float* x   = (const float*)d_in[0];
    const float* Wt  = (const float*)d_in[1];
    const float* bt  = (const float*)d_in[2];
    const float* gt  = (const float*)d_in[3];
    const float* bet = (const float*)d_in[4];
    const float* Ws  = (const float*)d_in[5];
    const float* bs  = (const float*)d_in[6];
    const float* gs  = (const float*)d_in[7];
    const float* bes = (const float*)d_in[8];
    const float* W2  = (const float*)d_in[9];
    const float* b2  = (const float*)d_in[10];
    float* out = (float*)d_out;

    char* wsb = (char*)d_ws;
    unsigned* mb = (unsigned*)wsb;                       // 256 B
    float* gates = (float*)(wsb + 256);                  // 2048 B
    unsigned short* WtTh = (unsigned short*)(wsb + 4096);
    unsigned short* WtTl = WtTh + (size_t)ND * NH;
    unsigned short* WsTh = WtTl + (size_t)ND * NH;
    unsigned short* WsTl = WsTh + (size_t)ND * NH;

    hipMemsetAsync(d_out, 0, sizeof(float) * NB * NL * NE, stream);
    hipMemsetAsync(mb, 0, 256, stream);

    wprep<<<256, 256, 0, stream>>>(Wt, Ws, WtTh, WtTl, WsTh, WsTl);
    fused_mfma<<<NROWS / BM, THREADS, 0, stream>>>(
        x, bt, gt, bet, bs, gs, bes, W2, b2,
        WtTh, WtTl, WsTh, WsTl, mb, gates);
    finalize_k<<<1, 64, 0, stream>>>(mb, gates, out);
}

// Round 3
// 219.733 us; speedup vs baseline: 2.7785x; 1.2808x over previous
//
#include <hip/hip_runtime.h>

#define NB 32
#define NL 512
#define ND 512
#define NH 1024
#define NE 8
#define NROWS (NB * NL)       // 16384
#define NTILES (NROWS / 64)   // 256

typedef __attribute__((ext_vector_type(8))) short bf16x8;
typedef __attribute__((ext_vector_type(4))) float f32x4;

__device__ __forceinline__ unsigned short f2bf(float f) {
    unsigned u = __float_as_uint(f);
    return (unsigned short)((u + 0x7fffu + ((u >> 16) & 1u)) >> 16);
}
__device__ __forceinline__ float bf2f(unsigned short b) {
    return __uint_as_float(((unsigned)b) << 16);
}
// split-bf16 pack of two adjacent values -> (hi u32, lo u32)
__device__ __forceinline__ unsigned pack2(float a0, float a1, unsigned& lo) {
    unsigned short h0 = f2bf(a0), h1 = f2bf(a1);
    unsigned short l0 = f2bf(a0 - bf2f(h0)), l1 = f2bf(a1 - bf2f(h1));
    lo = ((unsigned)l1 << 16) | l0;
    return ((unsigned)h1 << 16) | h0;
}

// ---------- W prep: transpose + split, packed [nt][kb][lane][jp] ----------
__global__ __launch_bounds__(256) void wprep(
    const float* __restrict__ Wt, const float* __restrict__ Ws,
    unsigned* __restrict__ bpack)
{
    __shared__ float tile[64][65];
    int bid = blockIdx.x;
    int mat = bid >> 7, rem = bid & 127;
    int kt0 = (rem >> 4) << 6;
    int nt0 = (rem & 15) << 6;
    const float* W = mat ? Ws : Wt;
    unsigned* Oh = bpack + (mat ? 2u : 0u) * 262144u;
    unsigned* Ol = Oh + 262144u;
    int t = threadIdx.x;
    #pragma unroll
    for (int i = 0; i < 16; ++i) {
        int idx = t + 256 * i;
        int k = idx >> 6, n = idx & 63;
        tile[k][n] = W[(size_t)(kt0 + k) * NH + nt0 + n];
    }
    __syncthreads();
    #pragma unroll
    for (int i = 0; i < 8; ++i) {
        int idx = t + 256 * i;                 // 2048 u32 positions
        int jp = idx & 3, lane = (idx >> 2) & 63, kbr = (idx >> 8) & 1, ntr = (idx >> 9) & 3;
        int ncol = ntr * 16 + (lane & 15);
        int kcol = kbr * 32 + ((lane >> 4) << 3) + jp * 2;
        float w0 = tile[kcol][ncol], w1 = tile[kcol + 1][ncol];
        unsigned lo, hi = pack2(w0, w1, lo);
        int nt = (nt0 >> 4) + ntr;
        int kb = (kt0 >> 5) + kbr;
        unsigned offs = ((unsigned)(nt * 16 + kb) * 64u + (unsigned)lane) * 4u + jp;
        Oh[offs] = hi;
        Ol[offs] = lo;
    }
}

// ---------- A prep: decomp (sliding MA) + split, fragment-packed per tile ----------
// apack per tile: [arr 0..3 = t_h,t_l,s_h,s_l][kb][mf][lane][jp]  (4 x 16384 u32)
__global__ __launch_bounds__(256) void aprep(
    const float* __restrict__ x, unsigned* __restrict__ apack, int t0)
{
    __shared__ float xt[88][131];
    __shared__ float ma[64][131];
    int tile = t0 + blockIdx.x;
    int row0 = tile * 64;
    int b = row0 >> 9, l0 = row0 & (NL - 1);
    const float* xb = x + (size_t)b * NL * ND;
    unsigned* base = apack + (size_t)blockIdx.x * 65536u;
    int tid = threadIdx.x;

    for (int kc = 0; kc < 4; ++kc) {
        int k0 = kc * 128;
        __syncthreads();
        #pragma unroll
        for (int i = 0; i < 44; ++i) {
            int idx = tid + 256 * i;          // 88*128 = 11264
            int rr = idx >> 7, cc = idx & 127;
            int ll = l0 - 12 + rr;
            ll = ll < 0 ? 0 : (ll > NL - 1 ? NL - 1 : ll);
            xt[rr][cc] = xb[(size_t)ll * ND + k0 + cc];
        }
        __syncthreads();
        {   // sliding 25-tap window along rows
            int cc = tid & 127, half = tid >> 7;
            int r0 = half * 32;
            float s = 0.f;
            #pragma unroll
            for (int t = 0; t < 25; ++t) s += xt[r0 + t][cc];
            ma[r0][cc] = s * (1.f / 25.f);
            for (int r = r0 + 1; r < r0 + 32; ++r) {
                s += xt[r + 24][cc] - xt[r - 1][cc];
                ma[r][cc] = s * (1.f / 25.f);
            }
        }
        __syncthreads();
        #pragma unroll
        for (int i = 0; i < 16; ++i) {
            int idx = tid + 256 * i;          // 4096 u32 per array
            int jp = idx & 3, lane = (idx >> 2) & 63, mf = (idx >> 8) & 3, kbr = (idx >> 10) & 3;
            int row = mf * 16 + (lane & 15);
            int kr = kbr * 32 + ((lane >> 4) << 3) + jp * 2;
            float m0 = ma[row][kr], m1 = ma[row][kr + 1];
            float x0 = xt[row + 12][kr], x1 = xt[row + 12][kr + 1];
            unsigned tlo, thi = pack2(x0 - m0, x1 - m1, tlo);
            unsigned slo, shi = pack2(m0, m1, slo);
            int kb = kc * 4 + kbr;
            unsigned offs = ((unsigned)(kb * 4 + mf) * 64u + (unsigned)lane) * 4u + jp;
            base[offs]          = thi;
            base[16384u + offs] = tlo;
            base[32768u + offs] = shi;
            base[49152u + offs] = slo;
        }
    }
}

// ---------- GEMM pass: pure-stream k-loop, LN epilogue ----------
// PASS 0: trend -> LN -> tstash (aliases consumed t-pack region)
// PASS 1: seasonal -> LN -> med=relu(t+s) -> W2 logits -> softmax/top2
template<int PASS>
__global__ __launch_bounds__(1024) void gemm_pass(
    const unsigned* __restrict__ apack, const unsigned* __restrict__ bpack,
    const float* __restrict__ bias, const float* __restrict__ gam, const float* __restrict__ bet,
    const float* __restrict__ W2, const float* __restrict__ b2,
    unsigned* __restrict__ mb, float* __restrict__ gates, int t0)
{
    __shared__ float stats[16][64][2];
    __shared__ float rowstat[64][2];
    __shared__ float lgp[16][64][NE];

    const int tid = threadIdx.x, lane = tid & 63, wave = tid >> 6;
    const int g = lane >> 4, c = lane & 15;
    const int ltile = blockIdx.x;
    const int tile = t0 + ltile;
    const int row0 = tile * 64;
    const int b = row0 >> 9, l0 = row0 & (NL - 1);

    const unsigned* Ah = apack + (size_t)ltile * 65536u + (PASS ? 32768u : 0u);
    const unsigned* Al = Ah + 16384u;
    const unsigned* Bh = bpack + (PASS ? 524288u : 0u);
    const unsigned* Bl = Bh + 262144u;
    unsigned short* tstash = (unsigned short*)(apack + (size_t)ltile * 65536u);

    f32x4 acc[4][4];
    #pragma unroll
    for (int cf = 0; cf < 4; ++cf)
        #pragma unroll
        for (int mf = 0; mf < 4; ++mf) acc[cf][mf] = (f32x4){0.f, 0.f, 0.f, 0.f};

    #pragma unroll 2
    for (int kb = 0; kb < 16; ++kb) {
        bf16x8 ah[4], al[4];
        #pragma unroll
        for (int mf = 0; mf < 4; ++mf) {
            unsigned ao = ((unsigned)(kb * 4 + mf) * 64u + (unsigned)lane) * 4u;
            ah[mf] = *(const bf16x8*)(Ah + ao);
            al[mf] = *(const bf16x8*)(Al + ao);
        }
        #pragma unroll
        for (int cf = 0; cf < 4; ++cf) {
            int nt = wave * 4 + cf;
            unsigned bo = ((unsigned)(nt * 16 + kb) * 64u + (unsigned)lane) * 4u;
            bf16x8 bh  = *(const bf16x8*)(Bh + bo);
            bf16x8 blv = *(const bf16x8*)(Bl + bo);
            #pragma unroll
            for (int mf = 0; mf < 4; ++mf) {
                acc[cf][mf] = __builtin_amdgcn_mfma_f32_16x16x32_bf16(ah[mf], bh,  acc[cf][mf], 0, 0, 0);
                acc[cf][mf] = __builtin_amdgcn_mfma_f32_16x16x32_bf16(al[mf], bh,  acc[cf][mf], 0, 0, 0);
                acc[cf][mf] = __builtin_amdgcn_mfma_f32_16x16x32_bf16(ah[mf], blv, acc[cf][mf], 0, 0, 0);
            }
        }
    }

    // ---- bias + row stats (sum/sumsq over N) ----
    float bv[4], gv[4], bev[4];
    #pragma unroll
    for (int cf = 0; cf < 4; ++cf) {
        int n = wave * 64 + cf * 16 + c;
        bv[cf] = bias[n]; gv[cf] = gam[n]; bev[cf] = bet[n];
    }
    #pragma unroll
    for (int cf = 0; cf < 4; ++cf)
        #pragma unroll
        for (int mf = 0; mf < 4; ++mf)
            #pragma unroll
            for (int r = 0; r < 4; ++r) acc[cf][mf][r] += bv[cf];

    #pragma unroll
    for (int mf = 0; mf < 4; ++mf)
        #pragma unroll
        for (int r = 0; r < 4; ++r) {
            float s = 0.f, q = 0.f;
            #pragma unroll
            for (int cf = 0; cf < 4; ++cf) { float v = acc[cf][mf][r]; s += v; q += v * v; }
            #pragma unroll
            for (int o = 1; o < 16; o <<= 1) { s += __shfl_xor(s, o); q += __shfl_xor(q, o); }
            if (c == 0) {
                int row = mf * 16 + g * 4 + r;
                stats[wave][row][0] = s;
                stats[wave][row][1] = q;
            }
        }
    __syncthreads();   // also orders: all waves done reading A before tstash alias write
    if (tid < 64) {
        float s = 0.f, q = 0.f;
        #pragma unroll
        for (int w = 0; w < 16; ++w) { s += stats[w][tid][0]; q += stats[w][tid][1]; }
        float mu = s * (1.f / NH);
        float var = q * (1.f / NH) - mu * mu;
        rowstat[tid][0] = mu;
        rowstat[tid][1] = rsqrtf(var + 1e-5f);
    }
    __syncthreads();

    if (PASS == 0) {
        #pragma unroll
        for (int mf = 0; mf < 4; ++mf)
            #pragma unroll
            for (int r = 0; r < 4; ++r) {
                int row = mf * 16 + g * 4 + r;
                float mu = rowstat[row][0], rs = rowstat[row][1];
                #pragma unroll
                for (int cf = 0; cf < 4; ++cf) {
                    int n = wave * 64 + cf * 16 + c;
                    tstash[row * 1024 + n] = f2bf((acc[cf][mf][r] - mu) * rs * gv[cf] + bev[cf]);
                }
            }
    } else {
        float w2v[4][NE];
        #pragma unroll
        for (int cf = 0; cf < 4; ++cf) {
            int n = wave * 64 + cf * 16 + c;
            const float4* wp = (const float4*)&W2[(size_t)n * NE];
            float4 a = wp[0], bq = wp[1];
            w2v[cf][0] = a.x;  w2v[cf][1] = a.y;  w2v[cf][2] = a.z;  w2v[cf][3] = a.w;
            w2v[cf][4] = bq.x; w2v[cf][5] = bq.y; w2v[cf][6] = bq.z; w2v[cf][7] = bq.w;
        }
        #pragma unroll
        for (int mf = 0; mf < 4; ++mf)
            #pragma unroll
            for (int r = 0; r < 4; ++r) {
                int row = mf * 16 + g * 4 + r;
                float mu = rowstat[row][0], rs = rowstat[row][1];
                float lg[NE];
                #pragma unroll
                for (int e = 0; e < NE; ++e) lg[e] = 0.f;
                #pragma unroll
                for (int cf = 0; cf < 4; ++cf) {
                    int n = wave * 64 + cf * 16 + c;
                    float sv = (acc[cf][mf][r] - mu) * rs * gv[cf] + bev[cf];
                    float tv = bf2f(tstash[row * 1024 + n]);
                    float m = tv + sv; m = m > 0.f ? m : 0.f;
                    #pragma unroll
                    for (int e = 0; e < NE; ++e) lg[e] = fmaf(m, w2v[cf][e], lg[e]);
                }
                #pragma unroll
                for (int o = 1; o < 16; o <<= 1)
                    #pragma unroll
                    for (int e = 0; e < NE; ++e) lg[e] += __shfl_xor(lg[e], o);
                if (c == 0)
                    #pragma unroll
                    for (int e = 0; e < NE; ++e) lgp[wave][row][e] = lg[e];
            }
        __syncthreads();
        if (tid < 64) {
            float lg[NE];
            #pragma unroll
            for (int e = 0; e < NE; ++e) {
                float s = b2[e];
                #pragma unroll
                for (int w = 0; w < 16; ++w) s += lgp[w][tid][e];
                lg[e] = s;
            }
            float mx = lg[0];
            #pragma unroll
            for (int e = 1; e < NE; ++e) mx = lg[e] > mx ? lg[e] : mx;
            float p[NE]; float sum = 0.f;
            #pragma unroll
            for (int e = 0; e < NE; ++e) { p[e] = expf(lg[e] - mx); sum += p[e]; }
            float inv = 1.f / sum;
            int i0 = 0;
            #pragma unroll
            for (int e = 1; e < NE; ++e) if (lg[e] > lg[i0]) i0 = e;
            int i1 = i0 == 0 ? 1 : 0;
            #pragma unroll
            for (int e = 0; e < NE; ++e) if (e != i0 && lg[e] > lg[i1]) i1 = e;
            atomicOr(&mb[2 * b + 0], 1u << i0);
            atomicOr(&mb[2 * b + 1], 1u << i1);
            if (l0 == 0 && tid < 8) {
                #pragma unroll
                for (int e = 0; e < NE; ++e)
                    gates[((size_t)b * 8 + tid) * NE + e] = p[e] * inv;
            }
        }
    }
}

// masked = gates * maskbit; denom = sum_b + 1e-4; out = masked/denom*64
__global__ void finalize_k(const unsigned* __restrict__ mb,
                           const float* __restrict__ gates,
                           float* __restrict__ out)
{
    int t = threadIdx.x;
    if (t >= 16) return;
    int l = t >> 1, e = t & 1;
    float m[NB];
    float sum = 0.f;
    #pragma unroll
    for (int bb = 0; bb < NB; ++bb) {
        float gvv = gates[((size_t)bb * 8 + l) * NE + e];
        float on  = ((mb[2 * bb + e] >> l) & 1u) ? 1.f : 0.f;
        m[bb] = gvv * on;
        sum += m[bb];
    }
    float scale = 64.f / (sum + 1e-4f);   // capacity = int(2.0*32)
    #pragma unroll
    for (int bb = 0; bb < NB; ++bb)
        out[(size_t)bb * (NL * NE) + l * NE + e] = m[bb] * scale;
}

extern "C" void kernel_launch(void* const* d_in, const int* in_sizes, int n_in,
                              void* d_out, int out_size, void* d_ws, size_t ws_size,
                              hipStream_t stream) {
    const float* x   = (const float*)d_in[0];
    const float* Wt  = (const float*)d_in[1];
    const float* bt  = (const float*)d_in[2];
    const float* gt  = (const float*)d_in[3];
    const float* bet = (const float*)d_in[4];
    const float* Ws  = (const float*)d_in[5];
    const float* bs  = (const float*)d_in[6];
    const float* gs  = (const float*)d_in[7];
    const float* bes = (const float*)d_in[8];
    const float* W2  = (const float*)d_in[9];
    const float* b2  = (const float*)d_in[10];
    float* out = (float*)d_out;

    char* wsb = (char*)d_ws;
    unsigned* mb    = (unsigned*)wsb;                       // 256 B
    float*    gates = (float*)(wsb + 256);                  // 2 KB
    unsigned* bpack = (unsigned*)(wsb + 4096);              // 4 MiB
    unsigned* apack = (unsigned*)(wsb + 4096 + 4194304);    // up to 64 MiB

    // phase the A-pack region to fit whatever ws we actually have
    size_t head = 4096 + 4194304;
    size_t avail = ws_size > head ? ws_size - head : 0;
    int tpp = (int)(avail / 262144);                        // 256 KiB per tile
    if (tpp > NTILES) tpp = NTILES;
    if (tpp < 1) tpp = 1;

    hipMemsetAsync(d_out, 0, sizeof(float) * NB * NL * NE, stream);
    hipMemsetAsync(mb, 0, 256, stream);

    wprep<<<256, 256, 0, stream>>>(Wt, Ws, bpack);
    for (int tptr = 0; tptr < NTILES; tptr += tpp) {
        int nt = NTILES - tptr < tpp ? NTILES - tptr : tpp;
        aprep<<<nt, 256, 0, stream>>>(x, apack, tptr);
        gemm_pass<0><<<nt, 1024, 0, stream>>>(apack, bpack, bt, gt, bet, W2, b2, mb, gates, tptr);
        gemm_pass<1><<<nt, 1024, 0, stream>>>(apack, bpack, bs, gs, bes, W2, b2, mb, gates, tptr);
    }
    finalize_k<<<1, 64, 0, stream>>>(mb, gates, out);
}